// Round 1
// baseline (140.078 us; speedup 1.0000x reference)
//
#include <hip/hip_runtime.h>

static constexpr int TILE = 256;

// Workspace layout (d_ws): double sums[2]  (sums[0]=huber_sum, sums[1]=rank_sum)
//                          unsigned long long cnt  at byte offset 16
// Total 24 bytes, zeroed via hipMemsetAsync each launch.

__global__ __launch_bounds__(TILE) void egl_pair_kernel(
    const float* __restrict__ pred, const float* __restrict__ targ, int n,
    double* __restrict__ sums, unsigned long long* __restrict__ cnt) {
  const int nT = (n + TILE - 1) / TILE;

  // Decode blockIdx.x -> upper-triangular tile pair (ti <= tj).
  int b = blockIdx.x;
  int ti = 0, rem = b;
  while (rem >= nT - ti) { rem -= (nT - ti); ++ti; }
  const int tj = ti + rem;

  __shared__ float sp[TILE];
  __shared__ float st[TILE];

  const int tid = threadIdx.x;
  const int j0 = tj * TILE;
  {
    int j = j0 + tid;
    sp[tid] = (j < n) ? pred[j] : 0.0f;
    st[tid] = (j < n) ? targ[j] : 0.0f;
  }
  __syncthreads();

  const int i = ti * TILE + tid;
  const bool ivalid = (i < n);
  const float pi  = ivalid ? pred[i] : 0.0f;
  const float tiv = ivalid ? targ[i] : 0.0f;

  float s = 0.0f;        // hinge sum partial
  unsigned int c = 0;    // masked pair count partial
  float hub = 0.0f;      // huber partial (diagonal blocks only)

  const int jcount = min(TILE, n - j0);

  if (ti == tj) {
    if (ivalid) {
      // Huber term for element i (each i covered exactly once across diag tiles)
      float d = pi - tiv;
      float ad = fabsf(d);
      hub = (ad < 1.0f) ? 0.5f * d * d : (ad - 0.5f);

      // pairs within tile: j > i  <=>  jj > tid
      for (int jj = tid + 1; jj < jcount; ++jj) {
        float tjv = st[jj];
        bool valid = (tjv != tiv);
        float sign = (tiv > tjv) ? 1.0f : -1.0f;
        float h = fmaxf(0.0f, 1.0f - sign * (pi - sp[jj]));
        s += valid ? h : 0.0f;
        c += valid ? 1u : 0u;
      }
    }
  } else {
    if (ivalid) {
      // all (i, j) with i in tile ti, j in tile tj (ti<tj => i<j always)
#pragma unroll 8
      for (int jj = 0; jj < jcount; ++jj) {
        float tjv = st[jj];
        bool valid = (tjv != tiv);
        float sign = (tiv > tjv) ? 1.0f : -1.0f;
        float h = fmaxf(0.0f, 1.0f - sign * (pi - sp[jj]));
        s += valid ? h : 0.0f;
        c += valid ? 1u : 0u;
      }
    }
  }

  // 64-lane wave reduction
  for (int off = 32; off > 0; off >>= 1) {
    s   += __shfl_down(s, off, 64);
    hub += __shfl_down(hub, off, 64);
    c   += __shfl_down(c, off, 64);
  }
  if ((tid & 63) == 0) {
    atomicAdd(&sums[1], (double)s);
    atomicAdd(&sums[0], (double)hub);
    atomicAdd(cnt, (unsigned long long)c);
  }
}

__global__ void egl_finalize(const double* __restrict__ sums,
                             const unsigned long long* __restrict__ cnt,
                             float* __restrict__ out, int n) {
  double huber = sums[0] / (double)n;
  unsigned long long c = *cnt;
  double rank = (c > 0) ? (sums[1] / (double)c) : 0.0;
  out[0] = (float)(0.7 * huber + 0.3 * rank);
}

extern "C" void kernel_launch(void* const* d_in, const int* in_sizes, int n_in,
                              void* d_out, int out_size, void* d_ws, size_t ws_size,
                              hipStream_t stream) {
  const float* pred = (const float*)d_in[0];
  const float* targ = (const float*)d_in[1];
  const int n = in_sizes[0];

  double* sums = (double*)d_ws;
  unsigned long long* cnt = (unsigned long long*)((char*)d_ws + 16);

  hipMemsetAsync(d_ws, 0, 24, stream);

  const int nT = (n + TILE - 1) / TILE;
  const int nblocks = nT * (nT + 1) / 2;
  egl_pair_kernel<<<nblocks, TILE, 0, stream>>>(pred, targ, n, sums, cnt);
  egl_finalize<<<1, 1, 0, stream>>>(sums, cnt, (float*)d_out, n);
}

// Round 2
// 69.935 us; speedup vs baseline: 2.0030x; 2.0030x over previous
//
#include <hip/hip_runtime.h>

static constexpr int TILE = 128;

// d_ws layout: float s_part[nb], c_part[nb], h_part[nb]  (nb = nT*(nT+1)/2)
// Every slot is written by its block each call -> no memset needed.

__global__ __launch_bounds__(TILE) void egl_pair_kernel(
    const float* __restrict__ pred, const float* __restrict__ targ, int n, int nT,
    float* __restrict__ ws_s, float* __restrict__ ws_c, float* __restrict__ ws_h) {
  // Decode blockIdx.x -> upper-triangular tile pair (ti <= tj).
  int b = blockIdx.x;
  int ti = 0, rem = b;
  while (rem >= nT - ti) { rem -= (nT - ti); ++ti; }
  const int tj = ti + rem;

  __shared__ alignas(16) float2 sj[TILE];   // (p_j, t_j)
  const int tid = threadIdx.x;
  const int j0 = tj * TILE;
  {
    int j = j0 + tid;
    float pj = (j < n) ? pred[j] : 0.0f;
    float tv = (j < n) ? targ[j] : 0.0f;
    sj[tid] = make_float2(pj, tv);
  }
  __syncthreads();

  const int i = ti * TILE + tid;
  const bool ivalid = (i < n);
  const float pi  = ivalid ? pred[i] : 0.0f;
  const float tiv = ivalid ? targ[i] : 0.0f;

  float s0 = 0.f, s1 = 0.f, s2 = 0.f, s3 = 0.f;   // hinge partials (4 chains)
  float c0 = 0.f, c1 = 0.f, c2 = 0.f, c3 = 0.f;   // count partials
  float hub = 0.f;                                 // huber (diag blocks only)

  const int jcount = min(TILE, n - j0);

  // per-pair math: sgn = clamp(t_i - t_j, -1, 1) in {-1,0,+1} (targets integer);
  // hinge = max(0, |sgn| - sgn*(p_i - p_j)); equal targets give exactly 0.
  if (ti != tj) {
    if (ivalid) {
      if (jcount == TILE) {
        const float4* sj4 = (const float4*)sj;   // 2 j's per 16B read
#pragma unroll
        for (int k = 0; k < TILE / 2; k += 2) {
          float4 a = sj4[k];
          float4 bq = sj4[k + 1];
          { float sg = fminf(fmaxf(tiv - a.y, -1.f), 1.f);
            s0 += fmaxf(fmaf(-sg, pi - a.x, fabsf(sg)), 0.f); c0 += fabsf(sg); }
          { float sg = fminf(fmaxf(tiv - a.w, -1.f), 1.f);
            s1 += fmaxf(fmaf(-sg, pi - a.z, fabsf(sg)), 0.f); c1 += fabsf(sg); }
          { float sg = fminf(fmaxf(tiv - bq.y, -1.f), 1.f);
            s2 += fmaxf(fmaf(-sg, pi - bq.x, fabsf(sg)), 0.f); c2 += fabsf(sg); }
          { float sg = fminf(fmaxf(tiv - bq.w, -1.f), 1.f);
            s3 += fmaxf(fmaf(-sg, pi - bq.z, fabsf(sg)), 0.f); c3 += fabsf(sg); }
        }
      } else {
        for (int jj = 0; jj < jcount; ++jj) {
          float2 a = sj[jj];
          float sg = fminf(fmaxf(tiv - a.y, -1.f), 1.f);
          s0 += fmaxf(fmaf(-sg, pi - a.x, fabsf(sg)), 0.f);
          c0 += fabsf(sg);
        }
      }
    }
  } else {
    if (ivalid) {
      float d = pi - tiv;
      float ad = fabsf(d);
      hub = (ad < 1.0f) ? 0.5f * d * d : (ad - 0.5f);
      for (int jj = tid + 1; jj < jcount; ++jj) {
        float2 a = sj[jj];
        float sg = fminf(fmaxf(tiv - a.y, -1.f), 1.f);
        s0 += fmaxf(fmaf(-sg, pi - a.x, fabsf(sg)), 0.f);
        c0 += fabsf(sg);
      }
    }
  }

  float s = (s0 + s1) + (s2 + s3);
  float c = (c0 + c1) + (c2 + c3);

  // 64-lane wave reduction
  for (int off = 32; off > 0; off >>= 1) {
    s   += __shfl_down(s, off, 64);
    c   += __shfl_down(c, off, 64);
    hub += __shfl_down(hub, off, 64);
  }
  __shared__ float red[2][3];
  if ((tid & 63) == 0) {
    int w = tid >> 6;
    red[w][0] = s; red[w][1] = c; red[w][2] = hub;
  }
  __syncthreads();
  if (tid == 0) {
    ws_s[b] = red[0][0] + red[1][0];
    ws_c[b] = red[0][1] + red[1][1];
    ws_h[b] = red[0][2] + red[1][2];
  }
}

__global__ __launch_bounds__(256) void egl_finalize(
    const float* __restrict__ ws_s, const float* __restrict__ ws_c,
    const float* __restrict__ ws_h, int nb, int n, float* __restrict__ out) {
  double s = 0.0, c = 0.0, h = 0.0;
  for (int idx = threadIdx.x; idx < nb; idx += 256) {
    s += (double)ws_s[idx];
    c += (double)ws_c[idx];
    h += (double)ws_h[idx];
  }
  for (int off = 32; off > 0; off >>= 1) {
    s += __shfl_down(s, off, 64);
    c += __shfl_down(c, off, 64);
    h += __shfl_down(h, off, 64);
  }
  __shared__ double red[4][3];
  int w = threadIdx.x >> 6;
  if ((threadIdx.x & 63) == 0) { red[w][0] = s; red[w][1] = c; red[w][2] = h; }
  __syncthreads();
  if (threadIdx.x == 0) {
    double S = 0.0, C = 0.0, H = 0.0;
    for (int k = 0; k < 4; ++k) { S += red[k][0]; C += red[k][1]; H += red[k][2]; }
    double huber = H / (double)n;
    double rank = (C > 0.0) ? (S / fmax(C, 1.0)) : 0.0;
    out[0] = (float)(0.7 * huber + 0.3 * rank);
  }
}

extern "C" void kernel_launch(void* const* d_in, const int* in_sizes, int n_in,
                              void* d_out, int out_size, void* d_ws, size_t ws_size,
                              hipStream_t stream) {
  const float* pred = (const float*)d_in[0];
  const float* targ = (const float*)d_in[1];
  const int n = in_sizes[0];

  const int nT = (n + TILE - 1) / TILE;
  const int nb = nT * (nT + 1) / 2;

  float* ws_s = (float*)d_ws;
  float* ws_c = ws_s + nb;
  float* ws_h = ws_c + nb;

  egl_pair_kernel<<<nb, TILE, 0, stream>>>(pred, targ, n, nT, ws_s, ws_c, ws_h);
  egl_finalize<<<1, 256, 0, stream>>>(ws_s, ws_c, ws_h, nb, n, (float*)d_out);
}